// Round 1
// baseline (277.694 us; speedup 1.0000x reference)
//
#include <hip/hip_runtime.h>

#define CH_EPS 1e-6f
#define TS 1024           // reference points per LDS tile (16 KB as float4)
#define NPTS 8192
#define NB 4

// Pack reference points as float4 (x, y, z, 0.5*(x^2+y^2+z^2)).
// Layout: w[0 .. 32768) = xyz2 points (refs for direction 0),
//         w[32768 .. 65536) = xyz1 points (refs for direction 1).
__global__ __launch_bounds__(256) void pack_kernel(
    const float* __restrict__ xyz1, const float* __restrict__ xyz2,
    float4* __restrict__ w) {
    int g = blockIdx.x * 256 + threadIdx.x;     // 0..65535
    const int half = NB * NPTS;                 // 32768
    const float* src = (g < half) ? xyz2 : xyz1;
    int p = (g < half) ? g : g - half;
    float a = src[3 * p], b = src[3 * p + 1], c = src[3 * p + 2];
    w[g] = make_float4(a, b, c, 0.5f * (a * a + b * b + c * c));
}

// One block = 256 query points (one per thread) for one (direction, batch).
// Loops all 8192 reference points in LDS tiles; tracks argmin of
// t = 0.5*|y|^2 - x.y  (equivalent argmin to squared distance).
// Epilogue: reconstruct d = 2t + |x|^2, gather NN normal, cosine term,
// block-reduce, atomicAdd scaled contributions to out[0], out[1].
__global__ __launch_bounds__(256) void chamfer_kernel(
    const float* __restrict__ xyz1, const float* __restrict__ xyz2,
    const float* __restrict__ nxyz1, const float* __restrict__ nxyz2,
    const float4* __restrict__ w, float* __restrict__ out) {
    __shared__ float4 sY[TS];
    __shared__ float red[2][4];

    const int tid = threadIdx.x;
    const int dir = blockIdx.y;   // 0: queries=xyz1 refs=xyz2 ; 1: swapped
    const int b   = blockIdx.z;
    const int i   = blockIdx.x * 256 + tid;

    const float* Q  = dir ? xyz2 : xyz1;
    const float* NQ = dir ? nxyz2 : nxyz1;
    const float* NR = dir ? nxyz1 : nxyz2;
    const float4* R = w + (size_t)dir * (NB * NPTS) + (size_t)b * NPTS;

    const size_t qoff = ((size_t)b * NPTS + i) * 3;
    const float x0 = Q[qoff], x1 = Q[qoff + 1], x2 = Q[qoff + 2];
    const float m0 = -x0, m1 = -x1, m2 = -x2;

    float bt0 = 1e30f, bt1 = 1e30f;
    int bi0 = 0, bi1 = 0;

    for (int tile = 0; tile < NPTS / TS; ++tile) {
        const float4* src = R + tile * TS;
        for (int k = tid; k < TS; k += 256) sY[k] = src[k];
        __syncthreads();
        const int base = tile * TS;
#pragma unroll 4
        for (int j = 0; j < TS; j += 2) {
            float4 ya = sY[j];
            float4 yb = sY[j + 1];
            float ta = fmaf(m0, ya.x, fmaf(m1, ya.y, fmaf(m2, ya.z, ya.w)));
            float tb = fmaf(m0, yb.x, fmaf(m1, yb.y, fmaf(m2, yb.z, yb.w)));
            if (ta < bt0) { bt0 = ta; bi0 = base + j; }
            if (tb < bt1) { bt1 = tb; bi1 = base + j + 1; }
        }
        __syncthreads();
    }

    float bt; int bi;
    if (bt1 < bt0) { bt = bt1; bi = bi1; } else { bt = bt0; bi = bi0; }

    // exact-ish squared distance of the selected neighbor
    float d = 2.0f * bt + (x0 * x0 + x1 * x1 + x2 * x2);

    // normal consistency term
    const float a0 = NQ[qoff], a1 = NQ[qoff + 1], a2 = NQ[qoff + 2];
    const size_t roff = ((size_t)b * NPTS + bi) * 3;
    const float c0 = NR[roff], c1 = NR[roff + 1], c2 = NR[roff + 2];
    float na = sqrtf(a0 * a0 + a1 * a1 + a2 * a2);
    float nc = sqrtf(c0 * c0 + c1 * c1 + c2 * c2);
    float cs = (a0 * c0 + a1 * c1 + a2 * c2) /
               (fmaxf(na, CH_EPS) * fmaxf(nc, CH_EPS));
    float cn = 1.0f - fabsf(cs);

    // wave (64-lane) reduction, then cross-wave via LDS
    for (int off = 32; off; off >>= 1) {
        d  += __shfl_down(d, off);
        cn += __shfl_down(cn, off);
    }
    const int lane = tid & 63, wv = tid >> 6;
    if (lane == 0) { red[0][wv] = d; red[1][wv] = cn; }
    __syncthreads();
    if (tid == 0) {
        float sd = red[0][0] + red[0][1] + red[0][2] + red[0][3];
        float sc = red[1][0] + red[1][1] + red[1][2] + red[1][3];
        const float inv = 1.0f / (float)(NB * NPTS);   // 1/32768
        atomicAdd(out + 0, sd * inv);
        atomicAdd(out + 1, sc * inv);
    }
}

extern "C" void kernel_launch(void* const* d_in, const int* in_sizes, int n_in,
                              void* d_out, int out_size, void* d_ws, size_t ws_size,
                              hipStream_t stream) {
    const float* xyz1  = (const float*)d_in[0];
    const float* xyz2  = (const float*)d_in[1];
    const float* nxyz1 = (const float*)d_in[2];
    const float* nxyz2 = (const float*)d_in[3];
    float* out = (float*)d_out;
    float4* w  = (float4*)d_ws;   // 65536 * 16 B = 1 MB

    hipMemsetAsync(d_out, 0, 2 * sizeof(float), stream);
    pack_kernel<<<dim3(2 * NB * NPTS / 256), dim3(256), 0, stream>>>(xyz1, xyz2, w);
    chamfer_kernel<<<dim3(NPTS / 256, 2, NB), dim3(256), 0, stream>>>(
        xyz1, xyz2, nxyz1, nxyz2, w, out);
}

// Round 2
// 170.117 us; speedup vs baseline: 1.6324x; 1.6324x over previous
//
#include <hip/hip_runtime.h>

#define CH_EPS 1e-6f
#define NPTS 8192
#define NB 4
#define NSEG 8
#define SEGSZ (NPTS / NSEG)        // 1024 refs per segment
#define NQ_TOT (2 * NB * NPTS)     // 65536 total (dir, batch, point) queries
#define BIGF 3.0e38f

// Pack reference points as float4 (x, y, z, 0.5*|p|^2).
// w[0 .. 32768) = xyz2 (refs for dir 0), w[32768 .. 65536) = xyz1 (refs for dir 1).
__global__ __launch_bounds__(256) void pack_kernel(
    const float* __restrict__ xyz1, const float* __restrict__ xyz2,
    float4* __restrict__ w) {
    int g = blockIdx.x * 256 + threadIdx.x;     // 0..65535
    const int half = NB * NPTS;                 // 32768
    const float* src = (g < half) ? xyz2 : xyz1;
    int p = (g < half) ? g : g - half;
    float a = src[3 * p], b = src[3 * p + 1], c = src[3 * p + 2];
    w[g] = make_float4(a, b, c, 0.5f * (a * a + b * b + c * c));
}

// Partial argmin: one block = 256 queries x one 1024-ref segment.
// t = 0.5*|y|^2 - x.y has the same argmin as |x-y|^2.
// Four independent accumulators for ILP; merged with index tie-break.
__global__ __launch_bounds__(256) void chamfer_partial(
    const float* __restrict__ xyz1, const float* __restrict__ xyz2,
    const float4* __restrict__ w, float2* __restrict__ part) {
    __shared__ float4 sY[SEGSZ];                // 16 KB

    const int tid = threadIdx.x;
    const int chunk = blockIdx.x;               // 0..31 query chunk
    const int seg = blockIdx.y;                 // 0..NSEG-1
    const int db = blockIdx.z;                  // 0..7
    const int dir = db >> 2, b = db & 3;
    const int i = chunk * 256 + tid;

    const float* Q = dir ? xyz2 : xyz1;
    const float4* R = w + dir * (NB * NPTS) + b * NPTS + seg * SEGSZ;

    // stage segment into LDS (coalesced, 4 x dwordx4 per thread)
    for (int k = tid; k < SEGSZ; k += 256) sY[k] = R[k];

    const size_t qoff = ((size_t)b * NPTS + i) * 3;
    const float m0 = -Q[qoff], m1 = -Q[qoff + 1], m2 = -Q[qoff + 2];

    float bt0 = BIGF, bt1 = BIGF, bt2 = BIGF, bt3 = BIGF;
    int bi0 = 0, bi1 = 0, bi2 = 0, bi3 = 0;

    __syncthreads();

#pragma unroll 2
    for (int j = 0; j < SEGSZ; j += 4) {
        float4 y0 = sY[j];
        float4 y1 = sY[j + 1];
        float4 y2 = sY[j + 2];
        float4 y3 = sY[j + 3];
        float t0 = fmaf(m0, y0.x, fmaf(m1, y0.y, fmaf(m2, y0.z, y0.w)));
        float t1 = fmaf(m0, y1.x, fmaf(m1, y1.y, fmaf(m2, y1.z, y1.w)));
        float t2 = fmaf(m0, y2.x, fmaf(m1, y2.y, fmaf(m2, y2.z, y2.w)));
        float t3 = fmaf(m0, y3.x, fmaf(m1, y3.y, fmaf(m2, y3.z, y3.w)));
        if (t0 < bt0) { bt0 = t0; bi0 = j; }
        if (t1 < bt1) { bt1 = t1; bi1 = j; }
        if (t2 < bt2) { bt2 = t2; bi2 = j; }
        if (t3 < bt3) { bt3 = t3; bi3 = j; }
    }

    // merge accumulators; exact argmin semantics (smallest index on ties)
    float bt = bt0; int bi = bi0 + 0;
    if (bt1 < bt || (bt1 == bt && bi1 + 1 < bi)) { bt = bt1; bi = bi1 + 1; }
    if (bt2 < bt || (bt2 == bt && bi2 + 2 < bi)) { bt = bt2; bi = bi2 + 2; }
    if (bt3 < bt || (bt3 == bt && bi3 + 3 < bi)) { bt = bt3; bi = bi3 + 3; }

    const int q = dir * (NB * NPTS) + b * NPTS + i;     // 0..65535
    part[(size_t)seg * NQ_TOT + q] =
        make_float2(bt, __int_as_float(seg * SEGSZ + bi));
}

// Merge NSEG partials per query, reconstruct distance, normal cosine term,
// block-reduce, atomicAdd into out[0] (chamfer) / out[1] (normals).
__global__ __launch_bounds__(256) void finalize_kernel(
    const float* __restrict__ xyz1, const float* __restrict__ xyz2,
    const float* __restrict__ nxyz1, const float* __restrict__ nxyz2,
    const float2* __restrict__ part, float* __restrict__ out) {
    __shared__ float red[2][4];

    const int tid = threadIdx.x;
    const int q = blockIdx.x * 256 + tid;       // 0..65535
    const int dir = q >> 15;
    const int rem = q & 32767;
    const int b = rem >> 13;
    const int i = rem & 8191;

    float2 p = part[q];
    float bt = p.x; int bi = __float_as_int(p.y);
    // segments are in ascending index order: strict < keeps earliest index
#pragma unroll
    for (int s = 1; s < NSEG; ++s) {
        float2 ps = part[(size_t)s * NQ_TOT + q];
        if (ps.x < bt) { bt = ps.x; bi = __float_as_int(ps.y); }
    }

    const float* Q  = dir ? xyz2 : xyz1;
    const float* NQp = dir ? nxyz2 : nxyz1;
    const float* NRp = dir ? nxyz1 : nxyz2;

    const size_t qoff = ((size_t)b * NPTS + i) * 3;
    const float x0 = Q[qoff], x1 = Q[qoff + 1], x2 = Q[qoff + 2];
    float d = 2.0f * bt + (x0 * x0 + x1 * x1 + x2 * x2);

    const float a0 = NQp[qoff], a1 = NQp[qoff + 1], a2 = NQp[qoff + 2];
    const size_t roff = ((size_t)b * NPTS + bi) * 3;
    const float c0 = NRp[roff], c1 = NRp[roff + 1], c2 = NRp[roff + 2];
    float na = sqrtf(a0 * a0 + a1 * a1 + a2 * a2);
    float nc = sqrtf(c0 * c0 + c1 * c1 + c2 * c2);
    float cs = (a0 * c0 + a1 * c1 + a2 * c2) /
               (fmaxf(na, CH_EPS) * fmaxf(nc, CH_EPS));
    float cn = 1.0f - fabsf(cs);

    for (int off = 32; off; off >>= 1) {
        d  += __shfl_down(d, off);
        cn += __shfl_down(cn, off);
    }
    const int lane = tid & 63, wv = tid >> 6;
    if (lane == 0) { red[0][wv] = d; red[1][wv] = cn; }
    __syncthreads();
    if (tid == 0) {
        float sd = red[0][0] + red[0][1] + red[0][2] + red[0][3];
        float sc = red[1][0] + red[1][1] + red[1][2] + red[1][3];
        const float inv = 1.0f / (float)(NB * NPTS);   // 1/32768
        atomicAdd(out + 0, sd * inv);
        atomicAdd(out + 1, sc * inv);
    }
}

extern "C" void kernel_launch(void* const* d_in, const int* in_sizes, int n_in,
                              void* d_out, int out_size, void* d_ws, size_t ws_size,
                              hipStream_t stream) {
    const float* xyz1  = (const float*)d_in[0];
    const float* xyz2  = (const float*)d_in[1];
    const float* nxyz1 = (const float*)d_in[2];
    const float* nxyz2 = (const float*)d_in[3];
    float* out = (float*)d_out;

    float4* w = (float4*)d_ws;                               // 1 MB
    float2* part = (float2*)((char*)d_ws + (size_t)NQ_TOT * sizeof(float4)); // 4 MB

    hipMemsetAsync(d_out, 0, 2 * sizeof(float), stream);
    pack_kernel<<<dim3(NQ_TOT / 256), dim3(256), 0, stream>>>(xyz1, xyz2, w);
    chamfer_partial<<<dim3(NPTS / 256, NSEG, 2 * NB), dim3(256), 0, stream>>>(
        xyz1, xyz2, w, part);
    finalize_kernel<<<dim3(NQ_TOT / 256), dim3(256), 0, stream>>>(
        xyz1, xyz2, nxyz1, nxyz2, part, out);
}

// Round 3
// 141.189 us; speedup vs baseline: 1.9668x; 1.2049x over previous
//
#include <hip/hip_runtime.h>

#define CH_EPS 1e-6f
#define NPTS 8192
#define NB 4
#define NSEG 16
#define SEGSZ (NPTS / NSEG)        // 512 refs per segment
#define QPT 4                      // queries per thread
#define QCHUNK (256 * QPT)         // 1024 queries per block
#define NQ_TOT (2 * NB * NPTS)     // 65536 total (dir, batch, point) queries
#define BIGF 3.0e38f

// Partial argmin: one block = 1024 queries (4/thread) x one 512-ref segment.
// t = 0.5*|y|^2 - x.y has the same argmin as |x-y|^2 (y-dependent part).
// Each block packs its own segment (x,y,z,0.5*|y|^2) into LDS, then scans.
// One ds_read_b128 serves QPT=4 queries -> DS pipe no longer limiting.
__global__ __launch_bounds__(256) void chamfer_partial(
    const float* __restrict__ xyz1, const float* __restrict__ xyz2,
    float2* __restrict__ part) {
    __shared__ float4 sY[SEGSZ];                // 8 KB

    const int tid = threadIdx.x;
    const int chunk = blockIdx.x;               // 0..7 (1024-query chunks)
    const int seg = blockIdx.y;                 // 0..NSEG-1
    const int db = blockIdx.z;                  // 0..7
    const int dir = db >> 2, b = db & 3;

    const float* Q = dir ? xyz2 : xyz1;         // queries
    const float* R = (dir ? xyz1 : xyz2) + ((size_t)b * NPTS + seg * SEGSZ) * 3;

    // pack this block's segment into LDS: (x, y, z, 0.5*|p|^2)
    for (int k = tid; k < SEGSZ; k += 256) {
        float a = R[3 * k], c = R[3 * k + 1], e = R[3 * k + 2];
        sY[k] = make_float4(a, c, e, 0.5f * (a * a + c * c + e * e));
    }

    // load QPT queries (negated coords so inner loop is pure FMA)
    float m[QPT][3];
    int qi[QPT];
#pragma unroll
    for (int q = 0; q < QPT; ++q) {
        qi[q] = chunk * QCHUNK + q * 256 + tid;
        const size_t off = ((size_t)b * NPTS + qi[q]) * 3;
        m[q][0] = -Q[off]; m[q][1] = -Q[off + 1]; m[q][2] = -Q[off + 2];
    }

    float bt[QPT];
    int bi[QPT];
#pragma unroll
    for (int q = 0; q < QPT; ++q) { bt[q] = BIGF; bi[q] = 0; }

    __syncthreads();

    for (int j = 0; j < SEGSZ; j += 2) {
        float4 y0 = sY[j];
        float4 y1 = sY[j + 1];
#pragma unroll
        for (int q = 0; q < QPT; ++q) {
            float t0 = fmaf(m[q][0], y0.x, fmaf(m[q][1], y0.y, fmaf(m[q][2], y0.z, y0.w)));
            float t1 = fmaf(m[q][0], y1.x, fmaf(m[q][1], y1.y, fmaf(m[q][2], y1.z, y1.w)));
            if (t0 < bt[q]) { bt[q] = t0; bi[q] = j; }
            if (t1 < bt[q]) { bt[q] = t1; bi[q] = j + 1; }
        }
    }

    const int qbase = dir * (NB * NPTS) + b * NPTS;
#pragma unroll
    for (int q = 0; q < QPT; ++q) {
        part[(size_t)seg * NQ_TOT + qbase + qi[q]] =
            make_float2(bt[q], __int_as_float(seg * SEGSZ + bi[q]));
    }
}

// Merge NSEG partials per query, reconstruct distance, normal cosine term,
// block-reduce, atomicAdd into out[0] (chamfer) / out[1] (normals).
__global__ __launch_bounds__(256) void finalize_kernel(
    const float* __restrict__ xyz1, const float* __restrict__ xyz2,
    const float* __restrict__ nxyz1, const float* __restrict__ nxyz2,
    const float2* __restrict__ part, float* __restrict__ out) {
    __shared__ float red[2][4];

    const int tid = threadIdx.x;
    const int q = blockIdx.x * 256 + tid;       // 0..65535
    const int dir = q >> 15;
    const int rem = q & 32767;
    const int b = rem >> 13;
    const int i = rem & 8191;

    float2 p = part[q];
    float bt = p.x; int bi = __float_as_int(p.y);
    // segments in ascending index order: strict < keeps earliest index
#pragma unroll
    for (int s = 1; s < NSEG; ++s) {
        float2 ps = part[(size_t)s * NQ_TOT + q];
        if (ps.x < bt) { bt = ps.x; bi = __float_as_int(ps.y); }
    }

    const float* Q   = dir ? xyz2 : xyz1;
    const float* NQp = dir ? nxyz2 : nxyz1;
    const float* NRp = dir ? nxyz1 : nxyz2;

    const size_t qoff = ((size_t)b * NPTS + i) * 3;
    const float x0 = Q[qoff], x1 = Q[qoff + 1], x2 = Q[qoff + 2];
    float d = 2.0f * bt + (x0 * x0 + x1 * x1 + x2 * x2);

    const float a0 = NQp[qoff], a1 = NQp[qoff + 1], a2 = NQp[qoff + 2];
    const size_t roff = ((size_t)b * NPTS + bi) * 3;
    const float c0 = NRp[roff], c1 = NRp[roff + 1], c2 = NRp[roff + 2];
    float na = sqrtf(a0 * a0 + a1 * a1 + a2 * a2);
    float nc = sqrtf(c0 * c0 + c1 * c1 + c2 * c2);
    float cs = (a0 * c0 + a1 * c1 + a2 * c2) /
               (fmaxf(na, CH_EPS) * fmaxf(nc, CH_EPS));
    float cn = 1.0f - fabsf(cs);

    for (int off = 32; off; off >>= 1) {
        d  += __shfl_down(d, off);
        cn += __shfl_down(cn, off);
    }
    const int lane = tid & 63, wv = tid >> 6;
    if (lane == 0) { red[0][wv] = d; red[1][wv] = cn; }
    __syncthreads();
    if (tid == 0) {
        float sd = red[0][0] + red[0][1] + red[0][2] + red[0][3];
        float sc = red[1][0] + red[1][1] + red[1][2] + red[1][3];
        const float inv = 1.0f / (float)(NB * NPTS);   // 1/32768
        atomicAdd(out + 0, sd * inv);
        atomicAdd(out + 1, sc * inv);
    }
}

extern "C" void kernel_launch(void* const* d_in, const int* in_sizes, int n_in,
                              void* d_out, int out_size, void* d_ws, size_t ws_size,
                              hipStream_t stream) {
    const float* xyz1  = (const float*)d_in[0];
    const float* xyz2  = (const float*)d_in[1];
    const float* nxyz1 = (const float*)d_in[2];
    const float* nxyz2 = (const float*)d_in[3];
    float* out = (float*)d_out;
    float2* part = (float2*)d_ws;               // NSEG * 65536 * 8 B = 8 MB

    hipMemsetAsync(d_out, 0, 2 * sizeof(float), stream);
    chamfer_partial<<<dim3(NPTS / QCHUNK, NSEG, 2 * NB), dim3(256), 0, stream>>>(
        xyz1, xyz2, part);
    finalize_kernel<<<dim3(NQ_TOT / 256), dim3(256), 0, stream>>>(
        xyz1, xyz2, nxyz1, nxyz2, part, out);
}

// Round 4
// 138.374 us; speedup vs baseline: 2.0068x; 1.0203x over previous
//
#include <hip/hip_runtime.h>

#define CH_EPS 1e-6f
#define NPTS 8192
#define NB 4
#define NSEG 16
#define SEGSZ (NPTS / NSEG)        // 512 refs per segment
#define QPT 8                      // queries per thread
#define QCHUNK (256 * QPT)         // 2048 queries per block
#define NQ_TOT (2 * NB * NPTS)     // 65536 total (dir, batch, point) queries
#define BIGF 3.0e38f
#define IDXMASK 0xFFFFE000u        // keep 19 high bits of t, stuff 13-bit index

// Partial argmin: one block = 2048 queries (8/thread) x one 512-ref segment.
// t = 0.5*|y|^2 - x.y has the same argmin as |x-y|^2 (y-dependent part).
// Argmin via mantissa-stuffing: key = (bits(t) & IDXMASK) | global_ref_idx,
// tracked with a single fminf chain. Finalize decodes idx and recomputes the
// EXACT distance from coordinates, so stuffing only risks near-tie selection
// (relative margin < 2^-10) -- negligible in a 32768-point mean.
__global__ __launch_bounds__(256) void chamfer_partial(
    const float* __restrict__ xyz1, const float* __restrict__ xyz2,
    float* __restrict__ part) {
    __shared__ float4 sY[SEGSZ];                // 8 KB

    const int tid = threadIdx.x;
    const int chunk = blockIdx.x;               // 0..3 (2048-query chunks)
    const int seg = blockIdx.y;                 // 0..NSEG-1
    const int db = blockIdx.z;                  // 0..7
    const int dir = db >> 2, b = db & 3;

    const float* Q = dir ? xyz2 : xyz1;         // queries
    const float* R = (dir ? xyz1 : xyz2) + ((size_t)b * NPTS + seg * SEGSZ) * 3;

    // pack this block's segment into LDS: (x, y, z, 0.5*|p|^2)
    for (int k = tid; k < SEGSZ; k += 256) {
        float a = R[3 * k], c = R[3 * k + 1], e = R[3 * k + 2];
        sY[k] = make_float4(a, c, e, 0.5f * (a * a + c * c + e * e));
    }

    // load QPT queries (negated coords so inner loop is pure FMA)
    float m0[QPT], m1[QPT], m2[QPT], bt[QPT];
    int qi0;
    {
        qi0 = chunk * QCHUNK + tid;
#pragma unroll
        for (int q = 0; q < QPT; ++q) {
            const size_t off = ((size_t)b * NPTS + qi0 + q * 256) * 3;
            m0[q] = -Q[off]; m1[q] = -Q[off + 1]; m2[q] = -Q[off + 2];
            bt[q] = BIGF;
        }
    }

    __syncthreads();

    const unsigned gbase = seg * SEGSZ;         // global ref index base (uniform)

    float4 y0 = sY[0];
    float4 y1 = sY[1];
    for (int j = 0; j < SEGSZ; j += 2) {
        float4 c0 = y0, c1 = y1;
        if (j + 2 < SEGSZ) { y0 = sY[j + 2]; y1 = sY[j + 3]; }
        const unsigned g0 = gbase + j, g1 = gbase + j + 1;
#pragma unroll
        for (int q = 0; q < QPT; ++q) {
            float t0 = fmaf(m0[q], c0.x, fmaf(m1[q], c0.y, fmaf(m2[q], c0.z, c0.w)));
            float t1 = fmaf(m0[q], c1.x, fmaf(m1[q], c1.y, fmaf(m2[q], c1.z, c1.w)));
            float k0 = __uint_as_float((__float_as_uint(t0) & IDXMASK) | g0);
            float k1 = __uint_as_float((__float_as_uint(t1) & IDXMASK) | g1);
            bt[q] = fminf(bt[q], k0);
            bt[q] = fminf(bt[q], k1);
        }
    }

    const int qbase = dir * (NB * NPTS) + b * NPTS + qi0;
#pragma unroll
    for (int q = 0; q < QPT; ++q) {
        part[(size_t)seg * NQ_TOT + qbase + q * 256] = bt[q];
    }
}

// Merge NSEG keyed partials per query (pure fminf), decode nearest index,
// recompute exact distance, normal cosine term, block-reduce, atomicAdd.
__global__ __launch_bounds__(256) void finalize_kernel(
    const float* __restrict__ xyz1, const float* __restrict__ xyz2,
    const float* __restrict__ nxyz1, const float* __restrict__ nxyz2,
    const float* __restrict__ part, float* __restrict__ out) {
    __shared__ float red[2][4];

    const int tid = threadIdx.x;
    const int q = blockIdx.x * 256 + tid;       // 0..65535
    const int dir = q >> 15;
    const int rem = q & 32767;
    const int b = rem >> 13;
    const int i = rem & 8191;

    float bt = part[q];
#pragma unroll
    for (int s = 1; s < NSEG; ++s) bt = fminf(bt, part[(size_t)s * NQ_TOT + q]);
    const int bi = (int)(__float_as_uint(bt) & 0x1FFFu);   // global ref index

    const float* Q   = dir ? xyz2 : xyz1;
    const float* Rp  = dir ? xyz1 : xyz2;
    const float* NQp = dir ? nxyz2 : nxyz1;
    const float* NRp = dir ? nxyz1 : nxyz2;

    const size_t qoff = ((size_t)b * NPTS + i) * 3;
    const size_t roff = ((size_t)b * NPTS + bi) * 3;
    const float x0 = Q[qoff], x1 = Q[qoff + 1], x2 = Q[qoff + 2];
    const float y0 = Rp[roff], y1 = Rp[roff + 1], y2 = Rp[roff + 2];
    const float e0 = x0 - y0, e1 = x1 - y1, e2 = x2 - y2;
    float d = e0 * e0 + e1 * e1 + e2 * e2;      // exact squared distance

    const float a0 = NQp[qoff], a1 = NQp[qoff + 1], a2 = NQp[qoff + 2];
    const float c0 = NRp[roff], c1 = NRp[roff + 1], c2 = NRp[roff + 2];
    float na = sqrtf(a0 * a0 + a1 * a1 + a2 * a2);
    float nc = sqrtf(c0 * c0 + c1 * c1 + c2 * c2);
    float cs = (a0 * c0 + a1 * c1 + a2 * c2) /
               (fmaxf(na, CH_EPS) * fmaxf(nc, CH_EPS));
    float cn = 1.0f - fabsf(cs);

    for (int off = 32; off; off >>= 1) {
        d  += __shfl_down(d, off);
        cn += __shfl_down(cn, off);
    }
    const int lane = tid & 63, wv = tid >> 6;
    if (lane == 0) { red[0][wv] = d; red[1][wv] = cn; }
    __syncthreads();
    if (tid == 0) {
        float sd = red[0][0] + red[0][1] + red[0][2] + red[0][3];
        float sc = red[1][0] + red[1][1] + red[1][2] + red[1][3];
        const float inv = 1.0f / (float)(NB * NPTS);   // 1/32768
        atomicAdd(out + 0, sd * inv);
        atomicAdd(out + 1, sc * inv);
    }
}

extern "C" void kernel_launch(void* const* d_in, const int* in_sizes, int n_in,
                              void* d_out, int out_size, void* d_ws, size_t ws_size,
                              hipStream_t stream) {
    const float* xyz1  = (const float*)d_in[0];
    const float* xyz2  = (const float*)d_in[1];
    const float* nxyz1 = (const float*)d_in[2];
    const float* nxyz2 = (const float*)d_in[3];
    float* out = (float*)d_out;
    float* part = (float*)d_ws;                 // NSEG * 65536 * 4 B = 4 MB

    hipMemsetAsync(d_out, 0, 2 * sizeof(float), stream);
    chamfer_partial<<<dim3(NPTS / QCHUNK, NSEG, 2 * NB), dim3(256), 0, stream>>>(
        xyz1, xyz2, part);
    finalize_kernel<<<dim3(NQ_TOT / 256), dim3(256), 0, stream>>>(
        xyz1, xyz2, nxyz1, nxyz2, part, out);
}